// Round 7
// baseline (439.950 us; speedup 1.0000x reference)
//
#include <hip/hip_runtime.h>
#include <math.h>

#define NPTS 262144
#define KCL  256
#define DDIM 64
#define ALPHA_DP 1.0f

#define ROWS_PER_WAVE 32
#define WAVES_PER_BLK 8
#define ROWS_PER_BLK  (ROWS_PER_WAVE * WAVES_PER_BLK)   // 256
#define NBLK_MAIN     (NPTS / ROWS_PER_BLK)             // 1024
#define NPART         (NPTS / ROWS_PER_WAVE)            // 8192

// ws float offsets
#define OFF_ELOGPI 32768
#define OFF_BASE   33024
#define OFF_KLB    33280
#define OFF_KLP    33281
#define OFF_PART   33537

#define LN2_F    0.6931471805599453f
#define LOG2PI_F 1.8378770664093453f

typedef _Float16 f16x8 __attribute__((ext_vector_type(8)));
typedef float    f32x4 __attribute__((ext_vector_type(4)));

__device__ __forceinline__ float digamma_f(float x) {
  float r = 0.0f;
  while (x < 6.0f) { r -= 1.0f / x; x += 1.0f; }
  float inv  = 1.0f / x;
  float inv2 = inv * inv;
  return r + logf(x) - 0.5f * inv
       - inv2 * (0.083333333333333333f
         - inv2 * (0.008333333333333333f
           - inv2 * 0.003968253968253968f));
}

// --- P1: stick-breaking terms + cumsum + KL(Beta) --------------------------
__global__ void dpmm_beta(const float* __restrict__ u, const float* __restrict__ v,
                          float* __restrict__ ws) {
  __shared__ float eb_s[KCL], e1b_s[KCL], klb_s[KCL];
  const int k = threadIdx.x;
  float uk = u[k], vk = v[k];
  float ds  = digamma_f(uk + vk);
  float eb  = digamma_f(uk) - ds;
  float e1b = digamma_f(vk) - ds;
  eb_s[k] = eb; e1b_s[k] = e1b;
  klb_s[k] = lgammaf(uk + vk) - lgammaf(uk) - lgammaf(vk)
           - (lgammaf(1.0f + ALPHA_DP) - lgammaf(ALPHA_DP))
           + (uk - 1.0f) * eb + (vk - ALPHA_DP) * e1b;
  __syncthreads();
  if (k == 0) {
    float run = 0.0f;
    for (int j = 0; j < KCL; ++j) { ws[OFF_ELOGPI + j] = eb_s[j] + run; run += e1b_s[j]; }
    double t = 0.0;
    for (int j = 0; j < KCL; ++j) t += (double)klb_s[j];
    ws[OFF_KLB] = (float)t;
  }
}

// --- P2: per-(k,d) W split + per-k base & KL parts (one wave per cluster) --
// Wp layout (fp16): idx = ((s*16 + T)*64 + lane)*8 + e
//   s=0..3: Wh, s=4..7: Wl for k-row ks*32 + g*8 + e; lane = g*16 + c15
//   cluster k at tile T=(k&15), lane-col c15=(k>>4)  (transposed: lane owns
//   16 contiguous pi columns in the MFMA C layout)
__global__ __launch_bounds__(64) void dpmm_w(
    const float* __restrict__ tau, const float* __restrict__ c,
    const float* __restrict__ n,   const float* __restrict__ B,
    const float* __restrict__ tau0, const float* __restrict__ c0,
    const float* __restrict__ n0,  const float* __restrict__ B0,
    float* __restrict__ ws) {
  const int k = blockIdx.x, d = threadIdx.x;
  _Float16* Wp = (_Float16*)ws;

  float nk = n[k], ck = c[k], n0k = n0[k], c0k = c0[k];
  float Bkd = B[k * DDIM + d],   tkd  = tau[k * DDIM + d];
  float B0kd = B0[k * DDIM + d], t0kd = tau0[k * DDIM + d];
  float Elam = nk / Bkd;
  float wb = Elam * tkd;        // coeff of x   (k-row d)
  float wa = -0.5f * Elam;      // coeff of x^2 (k-row 64+d)

  const int T = k & 15, c15k = k >> 4;
  {
    int kk = d;
    int ks = kk >> 5, g = (kk >> 3) & 3, e = kk & 7;
    int lanei = g * 16 + c15k;
    _Float16 h = (_Float16)wb, lo = (_Float16)(wb - (float)h);
    Wp[(( ks      * 16 + T) * 64 + lanei) * 8 + e] = h;
    Wp[(((4 + ks) * 16 + T) * 64 + lanei) * 8 + e] = lo;
  }
  {
    int kk = 64 + d;
    int ks = kk >> 5, g = (kk >> 3) & 3, e = kk & 7;
    int lanei = g * 16 + c15k;
    _Float16 h = (_Float16)wa, lo = (_Float16)(wa - (float)h);
    Wp[(( ks      * 16 + T) * 64 + lanei) * 8 + e] = h;
    Wp[(((4 + ks) * 16 + T) * 64 + lanei) * 8 + e] = lo;
  }

  float a = 0.5f * nk, a0 = 0.5f * n0k;
  float dga = digamma_f(a);
  float lga = lgammaf(a), lga0 = lgammaf(a0);
  float b = 0.5f * Bkd, b0 = 0.5f * B0kd;
  float klg = (a - a0) * dga - lga + lga0
            + a0 * (logf(b) - logf(b0)) + a * (b0 - b) / b;
  float dt = tkd - t0kd;
  float knq = Elam * dt * dt;
  float negLogB = -logf(Bkd);
  float et2 = Elam * tkd * tkd;

  #pragma unroll
  for (int off = 32; off; off >>= 1) {
    klg      += __shfl_xor(klg, off, 64);
    knq      += __shfl_xor(knq, off, 64);
    negLogB  += __shfl_xor(negLogB, off, 64);
    et2      += __shfl_xor(et2, off, 64);
  }
  if (d == 0) {
    float sumEloglam = (float)DDIM * (dga + LN2_F) + negLogB;
    ws[OFF_BASE + k] = ws[OFF_ELOGPI + k]
        + 0.5f * (sumEloglam - (float)DDIM * LOG2PI_F
                  - (float)DDIM / ck - et2);
    float kln = 0.5f * (float)DDIM * (c0k / ck - 1.0f + logf(ck / c0k))
              + 0.5f * c0k * knq;
    ws[OFF_KLP + k] = klg + kln;
  }
}

__device__ __forceinline__ void split8(const float* v, f16x8& h, f16x8& l) {
  #pragma unroll
  for (int e = 0; e < 8; ++e) {
    _Float16 hh = (_Float16)v[e];
    h[e] = hh;
    l[e] = (_Float16)(v[e] - (float)hh);
  }
}

extern __shared__ _Float16 W_sh[];   // 65536 fp16 = 128 KB

__global__ __launch_bounds__(512) void dpmm_mfma(
    const float* __restrict__ x, const _Float16* __restrict__ Wp,
    const float* __restrict__ base,
    float* __restrict__ pi, float* __restrict__ partial) {
  const int tid  = threadIdx.x;
  const int lane = tid & 63;
  const int w    = tid >> 6;
  const int g    = lane >> 4;
  const int c15  = lane & 15;

  // ---- issue x loads first (latency hides under W staging) ----
  const long row0 = (long)blockIdx.x * ROWS_PER_BLK + (long)w * ROWS_PER_WAVE;
  float4 xr_[2][4];
  #pragma unroll
  for (int sub = 0; sub < 2; ++sub) {
    const long r = row0 + sub * 16 + c15;
    const float* xr = x + r * DDIM + g * 8;
    xr_[sub][0] = *(const float4*)(xr + 0);
    xr_[sub][1] = *(const float4*)(xr + 4);
    xr_[sub][2] = *(const float4*)(xr + 32);
    xr_[sub][3] = *(const float4*)(xr + 36);
  }

  // ---- stage W (linear copy: global layout == LDS layout) ----
  {
    const float4* gsrc = (const float4*)Wp;     // 8192 float4
    float4* ldst = (float4*)W_sh;
    #pragma unroll
    for (int it = 0; it < 16; ++it) {
      int idx = it * 512 + tid;
      ldst[idx] = gsrc[idx];
    }
  }

  // ---- build A fragments (hi/lo fp16) ----
  f16x8 ah[2][4], al[2][4];
  #pragma unroll
  for (int sub = 0; sub < 2; ++sub) {
    float c0[8] = {xr_[sub][0].x, xr_[sub][0].y, xr_[sub][0].z, xr_[sub][0].w,
                   xr_[sub][1].x, xr_[sub][1].y, xr_[sub][1].z, xr_[sub][1].w};
    float c1[8] = {xr_[sub][2].x, xr_[sub][2].y, xr_[sub][2].z, xr_[sub][2].w,
                   xr_[sub][3].x, xr_[sub][3].y, xr_[sub][3].z, xr_[sub][3].w};
    float q0[8], q1[8];
    #pragma unroll
    for (int e = 0; e < 8; ++e) { q0[e] = c0[e]*c0[e]; q1[e] = c1[e]*c1[e]; }
    split8(c0, ah[sub][0], al[sub][0]);
    split8(c1, ah[sub][1], al[sub][1]);
    split8(q0, ah[sub][2], al[sub][2]);
    split8(q1, ah[sub][3], al[sub][3]);
  }

  // ---- init acc with base[cluster]; lane c15, tile T -> cluster c15*16+T ----
  f32x4 acc[2][16];
  #pragma unroll
  for (int T = 0; T < 16; ++T) {
    float bb = base[c15 * 16 + T];
    f32x4 bv = { bb, bb, bb, bb };
    acc[0][T] = bv; acc[1][T] = bv;
  }

  __syncthreads();

  // ---- split GEMM: Wh frags reused 4x, Wl reused 2x ----
  #pragma unroll
  for (int kk = 0; kk < 4; ++kk) {
    #pragma unroll
    for (int T = 0; T < 16; ++T) {
      f16x8 b = *(const f16x8*)&W_sh[(size_t)((kk * 16 + T) * 64 + lane) * 8];
      acc[0][T] = __builtin_amdgcn_mfma_f32_16x16x32_f16(ah[0][kk], b, acc[0][T], 0, 0, 0);
      acc[1][T] = __builtin_amdgcn_mfma_f32_16x16x32_f16(ah[1][kk], b, acc[1][T], 0, 0, 0);
      acc[0][T] = __builtin_amdgcn_mfma_f32_16x16x32_f16(al[0][kk], b, acc[0][T], 0, 0, 0);
      acc[1][T] = __builtin_amdgcn_mfma_f32_16x16x32_f16(al[1][kk], b, acc[1][T], 0, 0, 0);
    }
  }
  #pragma unroll
  for (int kk = 0; kk < 4; ++kk) {
    #pragma unroll
    for (int T = 0; T < 16; ++T) {
      f16x8 b = *(const f16x8*)&W_sh[(size_t)(((4 + kk) * 16 + T) * 64 + lane) * 8];
      acc[0][T] = __builtin_amdgcn_mfma_f32_16x16x32_f16(ah[0][kk], b, acc[0][T], 0, 0, 0);
      acc[1][T] = __builtin_amdgcn_mfma_f32_16x16x32_f16(ah[1][kk], b, acc[1][T], 0, 0, 0);
    }
  }

  // ---- softmax epilogue; row = g*4+j, lane c15 owns cols c15*16..+15 ----
  float wls = 0.0f;
  #pragma unroll
  for (int sub = 0; sub < 2; ++sub) {
    #pragma unroll
    for (int j = 0; j < 4; ++j) {
      float m = acc[sub][0][j];
      #pragma unroll
      for (int T = 1; T < 16; ++T) m = fmaxf(m, acc[sub][T][j]);
      m = fmaxf(m, __shfl_xor(m, 1, 64));
      m = fmaxf(m, __shfl_xor(m, 2, 64));
      m = fmaxf(m, __shfl_xor(m, 4, 64));
      m = fmaxf(m, __shfl_xor(m, 8, 64));
      float ev[16]; float s = 0.0f;
      #pragma unroll
      for (int T = 0; T < 16; ++T) { ev[T] = __expf(acc[sub][T][j] - m); s += ev[T]; }
      s += __shfl_xor(s, 1, 64);
      s += __shfl_xor(s, 2, 64);
      s += __shfl_xor(s, 4, 64);
      s += __shfl_xor(s, 8, 64);
      float rs = 1.0f / s;
      const long r = row0 + sub * 16 + g * 4 + j;
      float* pr = pi + r * KCL + c15 * 16;
      #pragma unroll
      for (int ch = 0; ch < 4; ++ch) {
        f32x4 pv = { ev[4*ch+0] * rs, ev[4*ch+1] * rs,
                     ev[4*ch+2] * rs, ev[4*ch+3] * rs };
        __builtin_nontemporal_store(pv, (f32x4*)(pr + 4 * ch));  // NT + contiguous
      }
      wls += m + __logf(s);
    }
  }
  wls += __shfl_xor(wls, 16, 64);
  wls += __shfl_xor(wls, 32, 64);
  if (lane == 0) partial[blockIdx.x * WAVES_PER_BLK + w] = wls;
}

__global__ void dpmm_fin(const float* __restrict__ ws,
                         float* __restrict__ out_elbo) {
  __shared__ double red[256];
  const int t = threadIdx.x;
  double s = 0.0;
  for (int i = t; i < NPART; i += 256) s += (double)ws[OFF_PART + i];
  s -= (double)ws[OFF_KLP + t];           // subtract per-cluster KL parts
  red[t] = s;
  __syncthreads();
  for (int off = 128; off; off >>= 1) {
    if (t < off) red[t] += red[t + off];
    __syncthreads();
  }
  if (t == 0) out_elbo[0] = (float)(red[0] - (double)ws[OFF_KLB]);
}

extern "C" void kernel_launch(void* const* d_in, const int* in_sizes, int n_in,
                              void* d_out, int out_size, void* d_ws, size_t ws_size,
                              hipStream_t stream) {
  const float* x    = (const float*)d_in[0];
  const float* u    = (const float*)d_in[1];
  const float* v    = (const float*)d_in[2];
  const float* tau  = (const float*)d_in[3];
  const float* c    = (const float*)d_in[4];
  const float* n    = (const float*)d_in[5];
  const float* B    = (const float*)d_in[6];
  const float* tau0 = (const float*)d_in[7];
  const float* c0   = (const float*)d_in[8];
  const float* n0   = (const float*)d_in[9];
  const float* B0   = (const float*)d_in[10];

  float* out = (float*)d_out;
  float* ws  = (float*)d_ws;

  (void)hipFuncSetAttribute((const void*)dpmm_mfma,
                            hipFuncAttributeMaxDynamicSharedMemorySize, 131072);

  dpmm_beta<<<1, KCL, 0, stream>>>(u, v, ws);
  dpmm_w<<<KCL, DDIM, 0, stream>>>(tau, c, n, B, tau0, c0, n0, B0, ws);

  const _Float16* Wp = (const _Float16*)ws;
  const float* base  = ws + OFF_BASE;
  float* partial     = ws + OFF_PART;

  dpmm_mfma<<<NBLK_MAIN, 512, 131072, stream>>>(x, Wp, base, out, partial);
  dpmm_fin<<<1, 256, 0, stream>>>(ws, out + (size_t)NPTS * KCL);
}

// Round 8
// 272.655 us; speedup vs baseline: 1.6136x; 1.6136x over previous
//
#include <hip/hip_runtime.h>
#include <math.h>

#define NPTS 262144
#define KCL  256
#define DDIM 64
#define ALPHA_DP 1.0f

#define ROWS_PER_WAVE 32
#define WAVES_PER_BLK 8
#define ROWS_PER_BLK  (ROWS_PER_WAVE * WAVES_PER_BLK)   // 256
#define NBLK_MAIN     (NPTS / ROWS_PER_BLK)             // 1024
#define NPART         (NPTS / ROWS_PER_WAVE)            // 8192

// ws float offsets
#define OFF_ELOGPI 32768
#define OFF_BASE   33024
#define OFF_KLB    33280
#define OFF_KLP    33281
#define OFF_PART   33537

#define LN2_F    0.6931471805599453f
#define LOG2PI_F 1.8378770664093453f

typedef _Float16 f16x8 __attribute__((ext_vector_type(8)));
typedef float    f32x4 __attribute__((ext_vector_type(4)));

__device__ __forceinline__ float digamma_f(float x) {
  float r = 0.0f;
  while (x < 6.0f) { r -= 1.0f / x; x += 1.0f; }
  float inv  = 1.0f / x;
  float inv2 = inv * inv;
  return r + logf(x) - 0.5f * inv
       - inv2 * (0.083333333333333333f
         - inv2 * (0.008333333333333333f
           - inv2 * 0.003968253968253968f));
}

// --- P1: stick-breaking terms + cumsum + KL(Beta) --------------------------
__global__ void dpmm_beta(const float* __restrict__ u, const float* __restrict__ v,
                          float* __restrict__ ws) {
  __shared__ float eb_s[KCL], e1b_s[KCL], klb_s[KCL];
  const int k = threadIdx.x;
  float uk = u[k], vk = v[k];
  float ds  = digamma_f(uk + vk);
  float eb  = digamma_f(uk) - ds;
  float e1b = digamma_f(vk) - ds;
  eb_s[k] = eb; e1b_s[k] = e1b;
  klb_s[k] = lgammaf(uk + vk) - lgammaf(uk) - lgammaf(vk)
           - (lgammaf(1.0f + ALPHA_DP) - lgammaf(ALPHA_DP))
           + (uk - 1.0f) * eb + (vk - ALPHA_DP) * e1b;
  __syncthreads();
  if (k == 0) {
    float run = 0.0f;
    for (int j = 0; j < KCL; ++j) { ws[OFF_ELOGPI + j] = eb_s[j] + run; run += e1b_s[j]; }
    double t = 0.0;
    for (int j = 0; j < KCL; ++j) t += (double)klb_s[j];
    ws[OFF_KLB] = (float)t;
  }
}

// --- P2: per-(k,d) W split + per-k base & KL parts (one wave per cluster) --
// Wp layout (fp16): idx = ((s*16 + T)*64 + lane)*8 + e
//   s=0..3: Wh, s=4..7: Wl for k-row ks*32 + g*8 + e; lane = g*16 + c15
//   cluster k at tile T=(k&15), lane-col c15=(k>>4)
__global__ __launch_bounds__(64) void dpmm_w(
    const float* __restrict__ tau, const float* __restrict__ c,
    const float* __restrict__ n,   const float* __restrict__ B,
    const float* __restrict__ tau0, const float* __restrict__ c0,
    const float* __restrict__ n0,  const float* __restrict__ B0,
    float* __restrict__ ws) {
  const int k = blockIdx.x, d = threadIdx.x;
  _Float16* Wp = (_Float16*)ws;

  float nk = n[k], ck = c[k], n0k = n0[k], c0k = c0[k];
  float Bkd = B[k * DDIM + d],   tkd  = tau[k * DDIM + d];
  float B0kd = B0[k * DDIM + d], t0kd = tau0[k * DDIM + d];
  float Elam = nk / Bkd;
  float wb = Elam * tkd;        // coeff of x   (k-row d)
  float wa = -0.5f * Elam;      // coeff of x^2 (k-row 64+d)

  const int T = k & 15, c15k = k >> 4;
  {
    int kk = d;
    int ks = kk >> 5, g = (kk >> 3) & 3, e = kk & 7;
    int lanei = g * 16 + c15k;
    _Float16 h = (_Float16)wb, lo = (_Float16)(wb - (float)h);
    Wp[(( ks      * 16 + T) * 64 + lanei) * 8 + e] = h;
    Wp[(((4 + ks) * 16 + T) * 64 + lanei) * 8 + e] = lo;
  }
  {
    int kk = 64 + d;
    int ks = kk >> 5, g = (kk >> 3) & 3, e = kk & 7;
    int lanei = g * 16 + c15k;
    _Float16 h = (_Float16)wa, lo = (_Float16)(wa - (float)h);
    Wp[(( ks      * 16 + T) * 64 + lanei) * 8 + e] = h;
    Wp[(((4 + ks) * 16 + T) * 64 + lanei) * 8 + e] = lo;
  }

  float a = 0.5f * nk, a0 = 0.5f * n0k;
  float dga = digamma_f(a);
  float lga = lgammaf(a), lga0 = lgammaf(a0);
  float b = 0.5f * Bkd, b0 = 0.5f * B0kd;
  float klg = (a - a0) * dga - lga + lga0
            + a0 * (logf(b) - logf(b0)) + a * (b0 - b) / b;
  float dt = tkd - t0kd;
  float knq = Elam * dt * dt;
  float negLogB = -logf(Bkd);
  float et2 = Elam * tkd * tkd;

  #pragma unroll
  for (int off = 32; off; off >>= 1) {
    klg      += __shfl_xor(klg, off, 64);
    knq      += __shfl_xor(knq, off, 64);
    negLogB  += __shfl_xor(negLogB, off, 64);
    et2      += __shfl_xor(et2, off, 64);
  }
  if (d == 0) {
    float sumEloglam = (float)DDIM * (dga + LN2_F) + negLogB;
    ws[OFF_BASE + k] = ws[OFF_ELOGPI + k]
        + 0.5f * (sumEloglam - (float)DDIM * LOG2PI_F
                  - (float)DDIM / ck - et2);
    float kln = 0.5f * (float)DDIM * (c0k / ck - 1.0f + logf(ck / c0k))
              + 0.5f * c0k * knq;
    ws[OFF_KLP + k] = klg + kln;
  }
}

__device__ __forceinline__ void split8(const float* v, f16x8& h, f16x8& l) {
  #pragma unroll
  for (int e = 0; e < 8; ++e) {
    _Float16 hh = (_Float16)v[e];
    h[e] = hh;
    l[e] = (_Float16)(v[e] - (float)hh);
  }
}

extern __shared__ _Float16 W_sh[];   // 65536 fp16 = 128 KB

__global__ __launch_bounds__(512) void dpmm_mfma(
    const float* __restrict__ x, const _Float16* __restrict__ Wp,
    const float* __restrict__ base,
    float* __restrict__ pi, float* __restrict__ partial) {
  const int tid  = threadIdx.x;
  const int lane = tid & 63;
  const int w    = tid >> 6;
  const int g    = lane >> 4;
  const int c15  = lane & 15;

  // ---- issue x loads first (latency hides under W staging) ----
  const long row0 = (long)blockIdx.x * ROWS_PER_BLK + (long)w * ROWS_PER_WAVE;
  float4 xr_[2][4];
  #pragma unroll
  for (int sub = 0; sub < 2; ++sub) {
    const long r = row0 + sub * 16 + c15;
    const float* xr = x + r * DDIM + g * 8;
    xr_[sub][0] = *(const float4*)(xr + 0);
    xr_[sub][1] = *(const float4*)(xr + 4);
    xr_[sub][2] = *(const float4*)(xr + 32);
    xr_[sub][3] = *(const float4*)(xr + 36);
  }

  // ---- stage W (linear copy: global layout == LDS layout) ----
  {
    const float4* gsrc = (const float4*)Wp;     // 8192 float4
    float4* ldst = (float4*)W_sh;
    #pragma unroll
    for (int it = 0; it < 16; ++it) {
      int idx = it * 512 + tid;
      ldst[idx] = gsrc[idx];
    }
  }

  // ---- build A fragments (hi/lo fp16) ----
  f16x8 ah[2][4], al[2][4];
  #pragma unroll
  for (int sub = 0; sub < 2; ++sub) {
    float c0[8] = {xr_[sub][0].x, xr_[sub][0].y, xr_[sub][0].z, xr_[sub][0].w,
                   xr_[sub][1].x, xr_[sub][1].y, xr_[sub][1].z, xr_[sub][1].w};
    float c1[8] = {xr_[sub][2].x, xr_[sub][2].y, xr_[sub][2].z, xr_[sub][2].w,
                   xr_[sub][3].x, xr_[sub][3].y, xr_[sub][3].z, xr_[sub][3].w};
    float q0[8], q1[8];
    #pragma unroll
    for (int e = 0; e < 8; ++e) { q0[e] = c0[e]*c0[e]; q1[e] = c1[e]*c1[e]; }
    split8(c0, ah[sub][0], al[sub][0]);
    split8(c1, ah[sub][1], al[sub][1]);
    split8(q0, ah[sub][2], al[sub][2]);
    split8(q1, ah[sub][3], al[sub][3]);
  }

  // ---- init acc with base[cluster]; lane c15, tile T -> cluster c15*16+T ----
  f32x4 acc[2][16];
  #pragma unroll
  for (int T = 0; T < 16; ++T) {
    float bb = base[c15 * 16 + T];
    f32x4 bv = { bb, bb, bb, bb };
    acc[0][T] = bv; acc[1][T] = bv;
  }

  __syncthreads();

  // ---- split GEMM: Wh frags reused 4x, Wl reused 2x ----
  #pragma unroll
  for (int kk = 0; kk < 4; ++kk) {
    #pragma unroll
    for (int T = 0; T < 16; ++T) {
      f16x8 b = *(const f16x8*)&W_sh[(size_t)((kk * 16 + T) * 64 + lane) * 8];
      acc[0][T] = __builtin_amdgcn_mfma_f32_16x16x32_f16(ah[0][kk], b, acc[0][T], 0, 0, 0);
      acc[1][T] = __builtin_amdgcn_mfma_f32_16x16x32_f16(ah[1][kk], b, acc[1][T], 0, 0, 0);
      acc[0][T] = __builtin_amdgcn_mfma_f32_16x16x32_f16(al[0][kk], b, acc[0][T], 0, 0, 0);
      acc[1][T] = __builtin_amdgcn_mfma_f32_16x16x32_f16(al[1][kk], b, acc[1][T], 0, 0, 0);
    }
  }
  #pragma unroll
  for (int kk = 0; kk < 4; ++kk) {
    #pragma unroll
    for (int T = 0; T < 16; ++T) {
      f16x8 b = *(const f16x8*)&W_sh[(size_t)(((4 + kk) * 16 + T) * 64 + lane) * 8];
      acc[0][T] = __builtin_amdgcn_mfma_f32_16x16x32_f16(ah[0][kk], b, acc[0][T], 0, 0, 0);
      acc[1][T] = __builtin_amdgcn_mfma_f32_16x16x32_f16(ah[1][kk], b, acc[1][T], 0, 0, 0);
    }
  }

  // ---- all waves done reading W_sh; reuse it as the store-bounce buffer ----
  __syncthreads();
  char* wbase = (char*)W_sh + (size_t)w * 16384;   // wave-private 16 KB

  // ---- softmax epilogue; row = g*4+j, lane c15 owns cols c15*16..+15 ----
  float wls = 0.0f;
  #pragma unroll 1
  for (int sub = 0; sub < 2; ++sub) {
    #pragma unroll
    for (int j = 0; j < 4; ++j) {
      float m = acc[sub][0][j];
      #pragma unroll
      for (int T = 1; T < 16; ++T) m = fmaxf(m, acc[sub][T][j]);
      m = fmaxf(m, __shfl_xor(m, 1, 64));
      m = fmaxf(m, __shfl_xor(m, 2, 64));
      m = fmaxf(m, __shfl_xor(m, 4, 64));
      m = fmaxf(m, __shfl_xor(m, 8, 64));
      float ev[16]; float s = 0.0f;
      #pragma unroll
      for (int T = 0; T < 16; ++T) { ev[T] = __expf(acc[sub][T][j] - m); s += ev[T]; }
      s += __shfl_xor(s, 1, 64);
      s += __shfl_xor(s, 2, 64);
      s += __shfl_xor(s, 4, 64);
      s += __shfl_xor(s, 8, 64);
      float rs = 1.0f / s;
      const int rl = g * 4 + j;                  // local row 0..15
      // LDS write, rot-swizzled: chunk ch of this lane's 16 cols
      #pragma unroll
      for (int ch = 0; ch < 4; ++ch) {
        int rot = (ch + c15 + (c15 >> 2)) & 3;
        f32x4 pv = { ev[4*ch+0] * rs, ev[4*ch+1] * rs,
                     ev[4*ch+2] * rs, ev[4*ch+3] * rs };
        *(f32x4*)(wbase + rl * 1024 + c15 * 64 + rot * 16) = pv;
      }
      wls += m + __logf(s);
    }
    // linear readback: lane owns bytes lane*16 of each row -> contiguous 1KB/instr
    const int c15r = lane >> 2, chr = lane & 3;
    const int rotr = (chr + c15r + (c15r >> 2)) & 3;
    #pragma unroll
    for (int i = 0; i < 16; ++i) {
      f32x4 pv = *(const f32x4*)(wbase + i * 1024 + c15r * 64 + rotr * 16);
      *(f32x4*)(pi + (size_t)(row0 + sub * 16 + i) * KCL + lane * 4) = pv;
    }
  }
  wls += __shfl_xor(wls, 16, 64);
  wls += __shfl_xor(wls, 32, 64);
  if (lane == 0) partial[blockIdx.x * WAVES_PER_BLK + w] = wls;
}

__global__ void dpmm_fin(const float* __restrict__ ws,
                         float* __restrict__ out_elbo) {
  __shared__ double red[256];
  const int t = threadIdx.x;
  double s = 0.0;
  for (int i = t; i < NPART; i += 256) s += (double)ws[OFF_PART + i];
  s -= (double)ws[OFF_KLP + t];
  red[t] = s;
  __syncthreads();
  for (int off = 128; off; off >>= 1) {
    if (t < off) red[t] += red[t + off];
    __syncthreads();
  }
  if (t == 0) out_elbo[0] = (float)(red[0] - (double)ws[OFF_KLB]);
}

extern "C" void kernel_launch(void* const* d_in, const int* in_sizes, int n_in,
                              void* d_out, int out_size, void* d_ws, size_t ws_size,
                              hipStream_t stream) {
  const float* x    = (const float*)d_in[0];
  const float* u    = (const float*)d_in[1];
  const float* v    = (const float*)d_in[2];
  const float* tau  = (const float*)d_in[3];
  const float* c    = (const float*)d_in[4];
  const float* n    = (const float*)d_in[5];
  const float* B    = (const float*)d_in[6];
  const float* tau0 = (const float*)d_in[7];
  const float* c0   = (const float*)d_in[8];
  const float* n0   = (const float*)d_in[9];
  const float* B0   = (const float*)d_in[10];

  float* out = (float*)d_out;
  float* ws  = (float*)d_ws;

  (void)hipFuncSetAttribute((const void*)dpmm_mfma,
                            hipFuncAttributeMaxDynamicSharedMemorySize, 131072);

  dpmm_beta<<<1, KCL, 0, stream>>>(u, v, ws);
  dpmm_w<<<KCL, DDIM, 0, stream>>>(tau, c, n, B, tau0, c0, n0, B0, ws);

  const _Float16* Wp = (const _Float16*)ws;
  const float* base  = ws + OFF_BASE;
  float* partial     = ws + OFF_PART;

  dpmm_mfma<<<NBLK_MAIN, 512, 131072, stream>>>(x, Wp, base, out, partial);
  dpmm_fin<<<1, 256, 0, stream>>>(ws, out + (size_t)NPTS * KCL);
}

// Round 9
// 177.198 us; speedup vs baseline: 2.4828x; 1.5387x over previous
//
#include <hip/hip_runtime.h>
#include <math.h>

#define NPTS 262144
#define KCL  256
#define DDIM 64
#define ALPHA_DP 1.0f

#define ROWS_PER_WAVE 16
#define WAVES_PER_BLK 4
#define ROWS_PER_BLK  (ROWS_PER_WAVE * WAVES_PER_BLK)   // 64
#define NBLK_MAIN     (NPTS / ROWS_PER_BLK)             // 4096
#define NPART         (NPTS / ROWS_PER_WAVE)            // 16384

// ws float offsets
#define OFF_ELOGPI 32768
#define OFF_BASE   33024
#define OFF_KLB    33280
#define OFF_KLP    33281
#define OFF_PART   33537

#define LN2_F    0.6931471805599453f
#define LOG2PI_F 1.8378770664093453f

typedef _Float16 f16x8 __attribute__((ext_vector_type(8)));
typedef float    f32x4 __attribute__((ext_vector_type(4)));

__device__ __forceinline__ float digamma_f(float x) {
  float r = 0.0f;
  while (x < 6.0f) { r -= 1.0f / x; x += 1.0f; }
  float inv  = 1.0f / x;
  float inv2 = inv * inv;
  return r + logf(x) - 0.5f * inv
       - inv2 * (0.083333333333333333f
         - inv2 * (0.008333333333333333f
           - inv2 * 0.003968253968253968f));
}

// --- P1: stick-breaking terms + cumsum + KL(Beta) --------------------------
__global__ void dpmm_beta(const float* __restrict__ u, const float* __restrict__ v,
                          float* __restrict__ ws) {
  __shared__ float eb_s[KCL], e1b_s[KCL], klb_s[KCL];
  const int k = threadIdx.x;
  float uk = u[k], vk = v[k];
  float ds  = digamma_f(uk + vk);
  float eb  = digamma_f(uk) - ds;
  float e1b = digamma_f(vk) - ds;
  eb_s[k] = eb; e1b_s[k] = e1b;
  klb_s[k] = lgammaf(uk + vk) - lgammaf(uk) - lgammaf(vk)
           - (lgammaf(1.0f + ALPHA_DP) - lgammaf(ALPHA_DP))
           + (uk - 1.0f) * eb + (vk - ALPHA_DP) * e1b;
  __syncthreads();
  if (k == 0) {
    float run = 0.0f;
    for (int j = 0; j < KCL; ++j) { ws[OFF_ELOGPI + j] = eb_s[j] + run; run += e1b_s[j]; }
    double t = 0.0;
    for (int j = 0; j < KCL; ++j) t += (double)klb_s[j];
    ws[OFF_KLB] = (float)t;
  }
}

// --- P2: per-(k,d) W split + per-k base & KL parts (one wave per cluster) --
// Wp layout (fp16): idx = ((s*16 + T)*64 + lane)*8 + e
//   s=0..3: Wh, s=4..7: Wl for k-row ks*32 + g*8 + e; lane = g*16 + c15
//   cluster k at tile T=(k&15), lane-col c15=(k>>4)
__global__ __launch_bounds__(64) void dpmm_w(
    const float* __restrict__ tau, const float* __restrict__ c,
    const float* __restrict__ n,   const float* __restrict__ B,
    const float* __restrict__ tau0, const float* __restrict__ c0,
    const float* __restrict__ n0,  const float* __restrict__ B0,
    float* __restrict__ ws) {
  const int k = blockIdx.x, d = threadIdx.x;
  _Float16* Wp = (_Float16*)ws;

  float nk = n[k], ck = c[k], n0k = n0[k], c0k = c0[k];
  float Bkd = B[k * DDIM + d],   tkd  = tau[k * DDIM + d];
  float B0kd = B0[k * DDIM + d], t0kd = tau0[k * DDIM + d];
  float Elam = nk / Bkd;
  float wb = Elam * tkd;        // coeff of x   (k-row d)
  float wa = -0.5f * Elam;      // coeff of x^2 (k-row 64+d)

  const int T = k & 15, c15k = k >> 4;
  {
    int kk = d;
    int ks = kk >> 5, g = (kk >> 3) & 3, e = kk & 7;
    int lanei = g * 16 + c15k;
    _Float16 h = (_Float16)wb, lo = (_Float16)(wb - (float)h);
    Wp[(( ks      * 16 + T) * 64 + lanei) * 8 + e] = h;
    Wp[(((4 + ks) * 16 + T) * 64 + lanei) * 8 + e] = lo;
  }
  {
    int kk = 64 + d;
    int ks = kk >> 5, g = (kk >> 3) & 3, e = kk & 7;
    int lanei = g * 16 + c15k;
    _Float16 h = (_Float16)wa, lo = (_Float16)(wa - (float)h);
    Wp[(( ks      * 16 + T) * 64 + lanei) * 8 + e] = h;
    Wp[(((4 + ks) * 16 + T) * 64 + lanei) * 8 + e] = lo;
  }

  float a = 0.5f * nk, a0 = 0.5f * n0k;
  float dga = digamma_f(a);
  float lga = lgammaf(a), lga0 = lgammaf(a0);
  float b = 0.5f * Bkd, b0 = 0.5f * B0kd;
  float klg = (a - a0) * dga - lga + lga0
            + a0 * (logf(b) - logf(b0)) + a * (b0 - b) / b;
  float dt = tkd - t0kd;
  float knq = Elam * dt * dt;
  float negLogB = -logf(Bkd);
  float et2 = Elam * tkd * tkd;

  #pragma unroll
  for (int off = 32; off; off >>= 1) {
    klg      += __shfl_xor(klg, off, 64);
    knq      += __shfl_xor(knq, off, 64);
    negLogB  += __shfl_xor(negLogB, off, 64);
    et2      += __shfl_xor(et2, off, 64);
  }
  if (d == 0) {
    float sumEloglam = (float)DDIM * (dga + LN2_F) + negLogB;
    ws[OFF_BASE + k] = ws[OFF_ELOGPI + k]
        + 0.5f * (sumEloglam - (float)DDIM * LOG2PI_F
                  - (float)DDIM / ck - et2);
    float kln = 0.5f * (float)DDIM * (c0k / ck - 1.0f + logf(ck / c0k))
              + 0.5f * c0k * knq;
    ws[OFF_KLP + k] = klg + kln;
  }
}

__device__ __forceinline__ void split8(const float* v, f16x8& h, f16x8& l) {
  #pragma unroll
  for (int e = 0; e < 8; ++e) {
    _Float16 hh = (_Float16)v[e];
    h[e] = hh;
    l[e] = (_Float16)(v[e] - (float)hh);
  }
}

// 16 rows/wave, 4 waves/block, W staged in 4x 32KB pieces -> 32KB static LDS,
// acc[16]=64 VGPR -> target 4 waves/SIMD (launch_bounds cap 128 VGPR).
__global__ __launch_bounds__(256, 4) void dpmm_mfma(
    const float* __restrict__ x, const _Float16* __restrict__ Wp,
    const float* __restrict__ base,
    float* __restrict__ pi, float* __restrict__ partial) {
  __shared__ _Float16 W_sh[2 * 16 * 64 * 8];   // 32 KB: two s-slices
  const int tid  = threadIdx.x;
  const int lane = tid & 63;
  const int w    = tid >> 6;
  const int g    = lane >> 4;
  const int c15  = lane & 15;

  // ---- issue x loads first ----
  const long row0 = (long)blockIdx.x * ROWS_PER_BLK + (long)w * ROWS_PER_WAVE;
  const long r = row0 + c15;                   // A-frag row = lane&15
  const float* xr = x + r * DDIM + g * 8;
  float4 x0 = *(const float4*)(xr + 0);
  float4 x1 = *(const float4*)(xr + 4);
  float4 x2 = *(const float4*)(xr + 32);
  float4 x3 = *(const float4*)(xr + 36);

  // ---- build A fragments (hi/lo fp16) ----
  f16x8 ah[4], al[4];
  {
    float c0[8] = {x0.x,x0.y,x0.z,x0.w,x1.x,x1.y,x1.z,x1.w};
    float c1[8] = {x2.x,x2.y,x2.z,x2.w,x3.x,x3.y,x3.z,x3.w};
    float q0[8], q1[8];
    #pragma unroll
    for (int e = 0; e < 8; ++e) { q0[e] = c0[e]*c0[e]; q1[e] = c1[e]*c1[e]; }
    split8(c0, ah[0], al[0]);   // k 0..31   : x
    split8(c1, ah[1], al[1]);   // k 32..63  : x
    split8(q0, ah[2], al[2]);   // k 64..95  : x^2
    split8(q1, ah[3], al[3]);   // k 96..127 : x^2
  }

  // ---- init acc with base[cluster]; lane c15, tile T -> cluster c15*16+T ----
  f32x4 acc[16];
  #pragma unroll
  for (int T = 0; T < 16; ++T) {
    float bb = base[c15 * 16 + T];
    f32x4 bv = { bb, bb, bb, bb };
    acc[T] = bv;
  }

  // ---- 4 stages of 32KB; q=0,1: Wh (2 MFMA per b-frag), q=2,3: Wl (1) ----
  #pragma unroll
  for (int q = 0; q < 4; ++q) {
    if (q) __syncthreads();                    // prev GEMM done reading W_sh
    {
      const float4* gsrc = (const float4*)Wp + (size_t)q * 2048;
      float4* ldst = (float4*)W_sh;
      #pragma unroll
      for (int it = 0; it < 8; ++it) {
        int idx = it * 256 + tid;
        ldst[idx] = gsrc[idx];
      }
    }
    __syncthreads();                           // stage complete
    #pragma unroll
    for (int sq = 0; sq < 2; ++sq) {
      if (q < 2) {
        const int kk = q * 2 + sq;
        #pragma unroll
        for (int T = 0; T < 16; ++T) {
          f16x8 b = *(const f16x8*)&W_sh[(size_t)((sq * 16 + T) * 64 + lane) * 8];
          acc[T] = __builtin_amdgcn_mfma_f32_16x16x32_f16(ah[kk], b, acc[T], 0, 0, 0);
          acc[T] = __builtin_amdgcn_mfma_f32_16x16x32_f16(al[kk], b, acc[T], 0, 0, 0);
        }
      } else {
        const int kk = (q - 2) * 2 + sq;
        #pragma unroll
        for (int T = 0; T < 16; ++T) {
          f16x8 b = *(const f16x8*)&W_sh[(size_t)((sq * 16 + T) * 64 + lane) * 8];
          acc[T] = __builtin_amdgcn_mfma_f32_16x16x32_f16(ah[kk], b, acc[T], 0, 0, 0);
        }
      }
    }
  }

  // ---- softmax epilogue; row = g*4+j, lane c15 owns cols c15*16..+15 ----
  float wls = 0.0f;
  #pragma unroll
  for (int j = 0; j < 4; ++j) {
    float m = acc[0][j];
    #pragma unroll
    for (int T = 1; T < 16; ++T) m = fmaxf(m, acc[T][j]);
    m = fmaxf(m, __shfl_xor(m, 1, 64));
    m = fmaxf(m, __shfl_xor(m, 2, 64));
    m = fmaxf(m, __shfl_xor(m, 4, 64));
    m = fmaxf(m, __shfl_xor(m, 8, 64));
    float ev[16]; float s = 0.0f;
    #pragma unroll
    for (int T = 0; T < 16; ++T) { ev[T] = __expf(acc[T][j] - m); s += ev[T]; }
    s += __shfl_xor(s, 1, 64);
    s += __shfl_xor(s, 2, 64);
    s += __shfl_xor(s, 4, 64);
    s += __shfl_xor(s, 8, 64);
    float rs = 1.0f / s;
    const long rr = row0 + g * 4 + j;
    float* pr = pi + (size_t)rr * KCL + c15 * 16;
    #pragma unroll
    for (int ch = 0; ch < 4; ++ch) {
      f32x4 pv = { ev[4*ch+0] * rs, ev[4*ch+1] * rs,
                   ev[4*ch+2] * rs, ev[4*ch+3] * rs };
      *(f32x4*)(pr + 4 * ch) = pv;
    }
    wls += m + __logf(s);       // uniform across each 16-lane group
  }
  wls += __shfl_xor(wls, 16, 64);
  wls += __shfl_xor(wls, 32, 64);
  if (lane == 0) partial[blockIdx.x * WAVES_PER_BLK + w] = wls;
}

__global__ void dpmm_fin(const float* __restrict__ ws,
                         float* __restrict__ out_elbo) {
  __shared__ double red[256];
  const int t = threadIdx.x;
  double s = 0.0;
  for (int i = t; i < NPART; i += 256) s += (double)ws[OFF_PART + i];
  s -= (double)ws[OFF_KLP + t];
  red[t] = s;
  __syncthreads();
  for (int off = 128; off; off >>= 1) {
    if (t < off) red[t] += red[t + off];
    __syncthreads();
  }
  if (t == 0) out_elbo[0] = (float)(red[0] - (double)ws[OFF_KLB]);
}

extern "C" void kernel_launch(void* const* d_in, const int* in_sizes, int n_in,
                              void* d_out, int out_size, void* d_ws, size_t ws_size,
                              hipStream_t stream) {
  const float* x    = (const float*)d_in[0];
  const float* u    = (const float*)d_in[1];
  const float* v    = (const float*)d_in[2];
  const float* tau  = (const float*)d_in[3];
  const float* c    = (const float*)d_in[4];
  const float* n    = (const float*)d_in[5];
  const float* B    = (const float*)d_in[6];
  const float* tau0 = (const float*)d_in[7];
  const float* c0   = (const float*)d_in[8];
  const float* n0   = (const float*)d_in[9];
  const float* B0   = (const float*)d_in[10];

  float* out = (float*)d_out;
  float* ws  = (float*)d_ws;

  dpmm_beta<<<1, KCL, 0, stream>>>(u, v, ws);
  dpmm_w<<<KCL, DDIM, 0, stream>>>(tau, c, n, B, tau0, c0, n0, B0, ws);

  const _Float16* Wp = (const _Float16*)ws;
  const float* base  = ws + OFF_BASE;
  float* partial     = ws + OFF_PART;

  dpmm_mfma<<<NBLK_MAIN, 256, 0, stream>>>(x, Wp, base, out, partial);
  dpmm_fin<<<1, 256, 0, stream>>>(ws, out + (size_t)NPTS * KCL);
}